// Round 4
// baseline (288.549 us; speedup 1.0000x reference)
//
#include <hip/hip_runtime.h>
#include <hip/hip_fp16.h>

#define B_ 64
#define T_ 2048
#define D_ 256
#define U_ 256
#define BT 256            // T rows per score_ctx block
#define NT (BT / 16)      // 16 tiles of 16 rows
#define TC (T_ / BT)      // 8 chunks per batch

typedef _Float16 half8  __attribute__((ext_vector_type(8)));
typedef float    floatx4 __attribute__((ext_vector_type(4)));

typedef const __attribute__((address_space(1))) void cg_void;   // global src for DMA
typedef __attribute__((address_space(3))) void       ls_void;   // LDS dst for DMA

// ---------------- Kernel 1 (fused prep): qproj (blocks 0..63) + w2t (blocks 64..127) ----------
__global__ void prep_kernel(const float* __restrict__ query,
                            const float* __restrict__ W1_w,
                            const float* __restrict__ W1_b,
                            const float* __restrict__ W2_w,
                            const float* __restrict__ W2_b,
                            float* __restrict__ qb,
                            _Float16* __restrict__ w2t) {
    __shared__ float sh[32 * 33];
    if (blockIdx.x < 64) {
        const int b = blockIdx.x;
        const int u = threadIdx.x;           // 256 threads
        sh[u] = query[b * D_ + u];
        __syncthreads();
        float acc = W1_b[u] + W2_b[u];
#pragma unroll 8
        for (int d = 0; d < D_; ++d)
            acc += sh[d] * W1_w[d * U_ + u];
        qb[b * U_ + u] = acc;
    } else {
        const int bid = blockIdx.x - 64;
        const int tu = bid & 7;
        const int td = bid >> 3;
        const int c  = threadIdx.x & 31;
        const int r0 = threadIdx.x >> 5;
        float* tile = sh;                    // [32][33]
#pragma unroll
        for (int i = 0; i < 4; ++i) {
            int r = r0 + i * 8;
            tile[r * 33 + c] = W2_w[(td * 32 + r) * U_ + tu * 32 + c];
        }
        __syncthreads();
#pragma unroll
        for (int i = 0; i < 4; ++i) {
            int r = r0 + i * 8;              // u within tile
            w2t[(tu * 32 + r) * D_ + td * 32 + c] = (_Float16)tile[c * 33 + r];
        }
    }
}

// ---------------- Kernel 2 (fused): w=exp(score) + partial context ----------------
// 512 threads = 8 waves; wave w owns u-range [w*32, w*32+32) -> bfrag = 64 VGPRs
// (TRULY register-stationary; R1-R3 at 64 u/wave needed 128 VGPRs and the compiler
// silently re-loaded W2 every tile -- VGPR_Count 96/112 was the tell).
// Plain __syncthreads 2-barrier loop, double-buffered global_load_lds(16B) staging,
// XOR-swizzled 16B-chunk layout (chunk cc of row r at chunk r*64 + (cc ^ (r&7))).
// No max-shift: |score| <= ||V_w||_1 ~ 10, exp safe in fp32 (verified R2/R3).
__launch_bounds__(512, 4)
__global__ void score_ctx_kernel(const float* __restrict__ values,
                                 const _Float16* __restrict__ w2t,
                                 const float* __restrict__ qb,
                                 const float* __restrict__ V_w,
                                 float* __restrict__ wexp,
                                 float* __restrict__ pctx,
                                 float* __restrict__ pl) {
    __shared__ __align__(16) float vbuf[2][16 * D_];   // 2 x 16KB fp32 tiles
    __shared__ __align__(16) float s_part[2][16][8];   // [phase][row][wave]
    __shared__ float csum[512];
    __shared__ float lsum[2];

    const int b     = blockIdx.y;
    const int chunk = blockIdx.x;
    const int tid   = threadIdx.x;
    const int wave  = tid >> 6;          // 0..7
    const int lane  = tid & 63;
    const int n16   = lane & 15;
    const int quad  = lane >> 4;
    const int u0    = wave * 32;

    // --- W2 B-fragments: 2 ut x 8 k x half8 = 64 VGPRs, register-stationary ---
    half8 bfrag[2][8];
#pragma unroll
    for (int ut = 0; ut < 2; ++ut) {
        const int u = u0 + ut * 16 + n16;
#pragma unroll
        for (int k = 0; k < 8; ++k)
            bfrag[ut][k] = *(const half8*)(w2t + u * D_ + k * 32 + quad * 8);
    }
    float qbv[2], vwv[2];
#pragma unroll
    for (int ut = 0; ut < 2; ++ut) {
        const int u = u0 + ut * 16 + n16;
        qbv[ut] = qb[b * U_ + u];
        vwv[ut] = V_w[u];
    }

    const float* vbase = values + (size_t)b * T_ * D_ + (size_t)chunk * BT * D_;

    auto stage = [&](int tile, int bi) {
        const float* src = vbase + tile * 16 * D_;
#pragma unroll
        for (int i = 0; i < 2; ++i) {
            const int r = wave * 2 + i;                          // wave-uniform row
            const float* g = src + r * D_ + ((lane ^ (r & 7)) << 2);
            float* l = &vbuf[bi][r * D_];                        // wave-uniform LDS base
            __builtin_amdgcn_global_load_lds((cg_void*)g, (ls_void*)l, 16, 0, 0);
        }
    };

    stage(0, 0);

    float c     = 0.f;       // context: this thread owns d = tid & 255 (half tile rows)
    float l_run = 0.f;       // sum of exp(score) over this thread's rows
    const int half = tid >> 8;           // 0: rows 0..7, 1: rows 8..15
    const int dd   = tid & 255;
    const int ccx  = dd >> 2, lo = dd & 3;

    float* wout = wexp + b * T_ + chunk * BT;

    for (int t = 0; t < NT; ++t) {
        __syncthreads();                          // tile t landed; ctx reads of t-1 done
        if (t + 1 < NT) stage(t + 1, (t + 1) & 1);

        // --- MFMA: Vp[16 x 32chunk] on vbuf[t&1] ---
        floatx4 acc[2] = {};
        const float* rowbase = &vbuf[t & 1][n16 * D_];
        const int swz = n16 & 7;
#pragma unroll
        for (int k = 0; k < 8; ++k) {
            const int c0 = k * 8 + quad * 2;
            floatx4 q0 = *(const floatx4*)(rowbase + (((c0    ) ^ swz) << 2));
            floatx4 q1 = *(const floatx4*)(rowbase + (((c0 + 1) ^ swz) << 2));
            half8 a;
            a[0] = (_Float16)q0.x; a[1] = (_Float16)q0.y;
            a[2] = (_Float16)q0.z; a[3] = (_Float16)q0.w;
            a[4] = (_Float16)q1.x; a[5] = (_Float16)q1.y;
            a[6] = (_Float16)q1.z; a[7] = (_Float16)q1.w;
#pragma unroll
            for (int ut = 0; ut < 2; ++ut)
                acc[ut] = __builtin_amdgcn_mfma_f32_16x16x32_f16(a, bfrag[ut][k], acc[ut], 0, 0, 0);
        }

        // --- epilogue: tanh + dot with V_w, butterfly over n16 ---
        float part[4];
#pragma unroll
        for (int r = 0; r < 4; ++r) {
            float s = 0.f;
#pragma unroll
            for (int ut = 0; ut < 2; ++ut) {
                float x  = acc[ut][r] + qbv[ut];
                float e  = __expf(2.f * x);
                float th = 1.f - __fdividef(2.f, e + 1.f);   // tanh(x)
                s += th * vwv[ut];
            }
            part[r] = s;
        }
#pragma unroll
        for (int m = 1; m < 16; m <<= 1)
#pragma unroll
            for (int r = 0; r < 4; ++r)
                part[r] += __shfl_xor(part[r], m, 16);
        if (n16 == 0)
#pragma unroll
            for (int r = 0; r < 4; ++r)
                s_part[t & 1][quad * 4 + r][wave] = part[r];

        __syncthreads();                          // s_part visible

        // --- context accumulate: halves split rows 0..7 / 8..15 ---
#pragma unroll
        for (int j = 0; j < 8; ++j) {
            const int r = half * 8 + j;
            floatx4 p0 = *(const floatx4*)&s_part[t & 1][r][0];
            floatx4 p1 = *(const floatx4*)&s_part[t & 1][r][4];
            float s = ((p0.x + p0.y) + (p0.z + p0.w)) + ((p1.x + p1.y) + (p1.z + p1.w));
            float w = __expf(s);
            l_run += w;
            c += w * vbuf[t & 1][r * D_ + ((ccx ^ (r & 7)) << 2) + lo];
            if (dd == j) wout[t * 16 + r] = w;    // one writer per row
        }
    }

    __syncthreads();
    csum[tid] = c;
    if (dd == 0) lsum[half] = l_run;
    __syncthreads();
    if (tid < 256) pctx[(b * TC + chunk) * D_ + tid] = csum[tid] + csum[tid + 256];
    if (tid == 0)  pl[b * TC + chunk] = lsum[0] + lsum[1];
}

// ---------------- Kernel 3: combine partials -> ctx, attn ----------------
__global__ void finalize_kernel(const float* __restrict__ pctx,
                                const float* __restrict__ pl,
                                const float* __restrict__ wexp,
                                float* __restrict__ ctx,
                                float* __restrict__ attn) {
    const int b = blockIdx.x, tid = threadIdx.x;   // 256 threads
    float L = 0.f;
#pragma unroll
    for (int i = 0; i < TC; ++i) L += pl[b * TC + i];
    const float invL = 1.f / L;
    float s = 0.f;
#pragma unroll
    for (int i = 0; i < TC; ++i) s += pctx[(b * TC + i) * D_ + tid];
    ctx[b * D_ + tid] = s * invL;
#pragma unroll
    for (int j = 0; j < T_ / 256; ++j) {
        const int t = j * 256 + tid;
        attn[b * T_ + t] = wexp[b * T_ + t] * invL;
    }
}

extern "C" void kernel_launch(void* const* d_in, const int* in_sizes, int n_in,
                              void* d_out, int out_size, void* d_ws, size_t ws_size,
                              hipStream_t stream) {
    const float* query  = (const float*)d_in[0];
    const float* values = (const float*)d_in[1];
    const float* W1_w   = (const float*)d_in[2];
    const float* W1_b   = (const float*)d_in[3];
    const float* W2_w   = (const float*)d_in[4];
    const float* W2_b   = (const float*)d_in[5];
    const float* V_w    = (const float*)d_in[6];
    // d_in[7] = V_b: softmax is shift-invariant -> no effect on either output.

    float* out  = (float*)d_out;
    float* ctx  = out;                  // [B, D]
    float* attn = out + B_ * D_;        // [B, T]

    char* ws = (char*)d_ws;
    float*    qb   = (float*)ws;                                 // B*U fp32     (64 KB)
    _Float16* w2t  = (_Float16*)(ws + (64 << 10));               // U*D fp16     (128 KB)
    float*    wexp = (float*)(ws + (192 << 10));                 // B*T fp32     (512 KB)
    float*    pctx = (float*)(ws + (704 << 10));                 // B*TC*D fp32  (512 KB)
    float*    pl   = (float*)(ws + (1216 << 10));                // B*TC fp32    (2 KB)

    prep_kernel     <<<dim3(128),     dim3(256), 0, stream>>>(query, W1_w, W1_b, W2_w, W2_b, qb, w2t);
    score_ctx_kernel<<<dim3(TC, B_),  dim3(512), 0, stream>>>(values, w2t, qb, V_w, wexp, pctx, pl);
    finalize_kernel <<<dim3(B_),      dim3(256), 0, stream>>>(pctx, pl, wexp, ctx, attn);
}

// Round 5
// 276.933 us; speedup vs baseline: 1.0419x; 1.0419x over previous
//
#include <hip/hip_runtime.h>
#include <hip/hip_fp16.h>

#define B_ 64
#define T_ 2048
#define D_ 256
#define U_ 256
#define BT 256            // T rows per score_ctx block
#define NT (BT / 16)      // 16 tiles of 16 rows
#define TC (T_ / BT)      // 8 chunks per batch

typedef _Float16 half8  __attribute__((ext_vector_type(8)));
typedef float    floatx4 __attribute__((ext_vector_type(4)));

typedef const __attribute__((address_space(1))) void cg_void;   // global src for DMA
typedef __attribute__((address_space(3))) void       ls_void;   // LDS dst for DMA

// ---------------- Kernel 1 (fused prep): qproj (blocks 0..63) + w2t (blocks 64..127) ----------
__global__ void prep_kernel(const float* __restrict__ query,
                            const float* __restrict__ W1_w,
                            const float* __restrict__ W1_b,
                            const float* __restrict__ W2_w,
                            const float* __restrict__ W2_b,
                            float* __restrict__ qb,
                            _Float16* __restrict__ w2t) {
    __shared__ float sh[32 * 33];
    if (blockIdx.x < 64) {
        const int b = blockIdx.x;
        const int u = threadIdx.x;           // 256 threads
        sh[u] = query[b * D_ + u];
        __syncthreads();
        float acc = W1_b[u] + W2_b[u];
#pragma unroll 8
        for (int d = 0; d < D_; ++d)
            acc += sh[d] * W1_w[d * U_ + u];
        qb[b * U_ + u] = acc;
    } else {
        const int bid = blockIdx.x - 64;
        const int tu = bid & 7;
        const int td = bid >> 3;
        const int c  = threadIdx.x & 31;
        const int r0 = threadIdx.x >> 5;
        float* tile = sh;                    // [32][33]
#pragma unroll
        for (int i = 0; i < 4; ++i) {
            int r = r0 + i * 8;
            tile[r * 33 + c] = W2_w[(td * 32 + r) * U_ + tu * 32 + c];
        }
        __syncthreads();
#pragma unroll
        for (int i = 0; i < 4; ++i) {
            int r = r0 + i * 8;              // u within tile
            w2t[(tu * 32 + r) * D_ + td * 32 + c] = (_Float16)tile[c * 33 + r];
        }
    }
}

// ---------------- Kernel 2 (fused): w=exp(score) + partial context ----------------
// 512 threads = 8 waves; wave w owns u-range [w*32, w*32+32).
// THE R1-R4 DISEASE: W2 B-fragments never stayed register-resident (VGPR_Count 96/112
// = per-tile L1/L2 rematerialization; R4's launch_bounds(512,4) cap 128 = scratch spill,
// WRITE_SIZE 25.8MB). FIX: pin bfrag into AGPRs (gfx950 MFMA reads B from AGPR directly)
// + launch_bounds(512,3) for a ~170 combined-reg cap. bfrag(64 AGPR) is now structurally
// outside the VGPR pool.
// Plain __syncthreads 2-barrier loop, double-buffered global_load_lds(16B) staging,
// XOR-swizzled 16B-chunk layout (chunk cc of row r at chunk r*64 + (cc ^ (r&7))).
// No max-shift: |score| <= ||V_w||_1 ~ 10, exp safe in fp32 (verified R2-R4).
__launch_bounds__(512, 3)
__global__ void score_ctx_kernel(const float* __restrict__ values,
                                 const _Float16* __restrict__ w2t,
                                 const float* __restrict__ qb,
                                 const float* __restrict__ V_w,
                                 float* __restrict__ wexp,
                                 float* __restrict__ pctx,
                                 float* __restrict__ pl) {
    __shared__ __align__(16) float vbuf[2][16 * D_];   // 2 x 16KB fp32 tiles
    __shared__ __align__(16) float s_part[2][16][8];   // [phase][row][wave]
    __shared__ float csum[512];
    __shared__ float lsum[2];

    const int b     = blockIdx.y;
    const int chunk = blockIdx.x;
    const int tid   = threadIdx.x;
    const int wave  = tid >> 6;          // 0..7
    const int lane  = tid & 63;
    const int n16   = lane & 15;
    const int quad  = lane >> 4;
    const int u0    = wave * 32;

    // --- W2 B-fragments: 2 ut x 8 k x half8 = 64 regs, PINNED to AGPRs ---
    half8 bfrag[2][8];
#pragma unroll
    for (int ut = 0; ut < 2; ++ut) {
        const int u = u0 + ut * 16 + n16;
#pragma unroll
        for (int k = 0; k < 8; ++k) {
            bfrag[ut][k] = *(const half8*)(w2t + u * D_ + k * 32 + quad * 8);
            asm volatile("" : "+a"(bfrag[ut][k]));   // force AGPR residence
        }
    }
    float qbv[2], vwv[2];
#pragma unroll
    for (int ut = 0; ut < 2; ++ut) {
        const int u = u0 + ut * 16 + n16;
        qbv[ut] = qb[b * U_ + u];
        vwv[ut] = V_w[u];
    }

    const float* vbase = values + (size_t)b * T_ * D_ + (size_t)chunk * BT * D_;

    auto stage = [&](int tile, int bi) {
        const float* src = vbase + tile * 16 * D_;
#pragma unroll
        for (int i = 0; i < 2; ++i) {
            const int r = wave * 2 + i;                          // wave-uniform row
            const float* g = src + r * D_ + ((lane ^ (r & 7)) << 2);
            float* l = &vbuf[bi][r * D_];                        // wave-uniform LDS base
            __builtin_amdgcn_global_load_lds((cg_void*)g, (ls_void*)l, 16, 0, 0);
        }
    };

    stage(0, 0);

    float c     = 0.f;       // context: this thread owns d = tid & 255 (half tile rows)
    float l_run = 0.f;       // sum of exp(score) over this thread's rows
    const int half = tid >> 8;           // 0: rows 0..7, 1: rows 8..15
    const int dd   = tid & 255;
    const int ccx  = dd >> 2, lo = dd & 3;

    float* wout = wexp + b * T_ + chunk * BT;

    for (int t = 0; t < NT; ++t) {
        __syncthreads();                          // tile t landed; ctx reads of t-1 done
        if (t + 1 < NT) stage(t + 1, (t + 1) & 1);

        // --- MFMA: Vp[16 x 32chunk] on vbuf[t&1] ---
        floatx4 acc[2] = {};
        const float* rowbase = &vbuf[t & 1][n16 * D_];
        const int swz = n16 & 7;
#pragma unroll
        for (int k = 0; k < 8; ++k) {
            const int c0 = k * 8 + quad * 2;
            floatx4 q0 = *(const floatx4*)(rowbase + (((c0    ) ^ swz) << 2));
            floatx4 q1 = *(const floatx4*)(rowbase + (((c0 + 1) ^ swz) << 2));
            half8 a;
            a[0] = (_Float16)q0.x; a[1] = (_Float16)q0.y;
            a[2] = (_Float16)q0.z; a[3] = (_Float16)q0.w;
            a[4] = (_Float16)q1.x; a[5] = (_Float16)q1.y;
            a[6] = (_Float16)q1.z; a[7] = (_Float16)q1.w;
#pragma unroll
            for (int ut = 0; ut < 2; ++ut)
                acc[ut] = __builtin_amdgcn_mfma_f32_16x16x32_f16(a, bfrag[ut][k], acc[ut], 0, 0, 0);
        }

        // --- epilogue: tanh + dot with V_w, butterfly over n16 ---
        float part[4];
#pragma unroll
        for (int r = 0; r < 4; ++r) {
            float s = 0.f;
#pragma unroll
            for (int ut = 0; ut < 2; ++ut) {
                float x  = acc[ut][r] + qbv[ut];
                float e  = __expf(2.f * x);
                float th = 1.f - __fdividef(2.f, e + 1.f);   // tanh(x)
                s += th * vwv[ut];
            }
            part[r] = s;
        }
#pragma unroll
        for (int m = 1; m < 16; m <<= 1)
#pragma unroll
            for (int r = 0; r < 4; ++r)
                part[r] += __shfl_xor(part[r], m, 16);
        if (n16 == 0)
#pragma unroll
            for (int r = 0; r < 4; ++r)
                s_part[t & 1][quad * 4 + r][wave] = part[r];

        __syncthreads();                          // s_part visible

        // --- context accumulate: halves split rows 0..7 / 8..15 ---
#pragma unroll
        for (int j = 0; j < 8; ++j) {
            const int r = half * 8 + j;
            floatx4 p0 = *(const floatx4*)&s_part[t & 1][r][0];
            floatx4 p1 = *(const floatx4*)&s_part[t & 1][r][4];
            float s = ((p0.x + p0.y) + (p0.z + p0.w)) + ((p1.x + p1.y) + (p1.z + p1.w));
            float w = __expf(s);
            l_run += w;
            c += w * vbuf[t & 1][r * D_ + ((ccx ^ (r & 7)) << 2) + lo];
            if (dd == j) wout[t * 16 + r] = w;    // one writer per row
        }
    }

    __syncthreads();
    csum[tid] = c;
    if (dd == 0) lsum[half] = l_run;
    __syncthreads();
    if (tid < 256) pctx[(b * TC + chunk) * D_ + tid] = csum[tid] + csum[tid + 256];
    if (tid == 0)  pl[b * TC + chunk] = lsum[0] + lsum[1];
}

// ---------------- Kernel 3: combine partials -> ctx, attn ----------------
__global__ void finalize_kernel(const float* __restrict__ pctx,
                                const float* __restrict__ pl,
                                const float* __restrict__ wexp,
                                float* __restrict__ ctx,
                                float* __restrict__ attn) {
    const int b = blockIdx.x, tid = threadIdx.x;   // 256 threads
    float L = 0.f;
#pragma unroll
    for (int i = 0; i < TC; ++i) L += pl[b * TC + i];
    const float invL = 1.f / L;
    float s = 0.f;
#pragma unroll
    for (int i = 0; i < TC; ++i) s += pctx[(b * TC + i) * D_ + tid];
    ctx[b * D_ + tid] = s * invL;
#pragma unroll
    for (int j = 0; j < T_ / 256; ++j) {
        const int t = j * 256 + tid;
        attn[b * T_ + t] = wexp[b * T_ + t] * invL;
    }
}

extern "C" void kernel_launch(void* const* d_in, const int* in_sizes, int n_in,
                              void* d_out, int out_size, void* d_ws, size_t ws_size,
                              hipStream_t stream) {
    const float* query  = (const float*)d_in[0];
    const float* values = (const float*)d_in[1];
    const float* W1_w   = (const float*)d_in[2];
    const float* W1_b   = (const float*)d_in[3];
    const float* W2_w   = (const float*)d_in[4];
    const float* W2_b   = (const float*)d_in[5];
    const float* V_w    = (const float*)d_in[6];
    // d_in[7] = V_b: softmax is shift-invariant -> no effect on either output.

    float* out  = (float*)d_out;
    float* ctx  = out;                  // [B, D]
    float* attn = out + B_ * D_;        // [B, T]

    char* ws = (char*)d_ws;
    float*    qb   = (float*)ws;                                 // B*U fp32     (64 KB)
    _Float16* w2t  = (_Float16*)(ws + (64 << 10));               // U*D fp16     (128 KB)
    float*    wexp = (float*)(ws + (192 << 10));                 // B*T fp32     (512 KB)
    float*    pctx = (float*)(ws + (704 << 10));                 // B*TC*D fp32  (512 KB)
    float*    pl   = (float*)(ws + (1216 << 10));                // B*TC fp32    (2 KB)

    prep_kernel     <<<dim3(128),     dim3(256), 0, stream>>>(query, W1_w, W1_b, W2_w, W2_b, qb, w2t);
    score_ctx_kernel<<<dim3(TC, B_),  dim3(512), 0, stream>>>(values, w2t, qb, V_w, wexp, pctx, pl);
    finalize_kernel <<<dim3(B_),      dim3(256), 0, stream>>>(pctx, pl, wexp, ctx, attn);
}